// Round 13
// baseline (385.327 us; speedup 1.0000x reference)
//
#include <hip/hip_runtime.h>
#include <math.h>

#define NB   4
#define CCH  512
#define LL   4096
#define GRP  32
#define CPG  16
#define CL   (CCH*LL)
#define EPSV 1e-5f
#define QSTR 1024   // QK fused row stride

typedef __bf16 bf16x8 __attribute__((ext_vector_type(8)));
typedef __bf16 bf16x4 __attribute__((ext_vector_type(4)));
typedef float  f32x4  __attribute__((ext_vector_type(4)));

#define GLOAD_LDS16(g, l) __builtin_amdgcn_global_load_lds( \
    (const __attribute__((address_space(1))) void*)(g),     \
    (__attribute__((address_space(3))) void*)(l), 16, 0, 0)

// ---------------------------------------------------------------------------
// Corrected XOR-swizzle (verified r6: conflicts 2.5e7 -> 6.3e6).
// ---------------------------------------------------------------------------
__device__ __forceinline__ int swz_slot(int row, int q) {
    return 4 * row + (q ^ ((row >> 1) & 3));
}
__device__ __forceinline__ void swz_src(int l, int& jj, int& cc) {
    jj = l >> 2;
    cc = (l & 3) ^ ((l >> 3) & 3);
}

#define DPPF(x, ctrl) __builtin_bit_cast(float, \
    __builtin_amdgcn_update_dpp(0, __builtin_bit_cast(int, (x)), (ctrl), 0xf, 0xf, false))
__device__ __forceinline__ float red_sum16(float x) {
    x += DPPF(x, 0xB1); x += DPPF(x, 0x4E);
    x += DPPF(x, 0x124); x += DPPF(x, 0x128);
    return x;
}

// ---------------------------------------------------------------------------
// GroupNorm pass 1 + weight convert, ONE launch (v18).
// Blocks [0,256): half-(n,g) groups, raw partial {s1,s2} (v15 scheme).
// Blocks [256,260): fp32->bf16 convert of wq|wk|wv|wo into Wb.
// ---------------------------------------------------------------------------
__global__ __launch_bounds__(1024) void gn_stats_w(const float* __restrict__ x,
    float* __restrict__ stats,
    const float* __restrict__ wq, const float* __restrict__ wk,
    const float* __restrict__ wv, const float* __restrict__ wo,
    __bf16* __restrict__ Wb) {
    if (blockIdx.x >= 256) {
        const int wi2 = blockIdx.x - 256;   // 0..3
        const float* sp = (wi2 == 0) ? wq : (wi2 == 1) ? wk
                        : (wi2 == 2) ? wv : wo;
        __bf16* d = Wb + (size_t)wi2 * CCH * CCH;
        for (int i = threadIdx.x * 4; i < CCH * CCH; i += 4096) {
            float4 v = *(const float4*)(sp + i);
            bf16x4 o; o[0]=(__bf16)v.x; o[1]=(__bf16)v.y; o[2]=(__bf16)v.z; o[3]=(__bf16)v.w;
            *(bf16x4*)(d + i) = o;
        }
        return;
    }
    int gid = blockIdx.x >> 1, h = blockIdx.x & 1;
    int n = gid >> 5, g = gid & 31;
    size_t base = ((size_t)n * CCH + (size_t)g * CPG) * LL
                + (size_t)h * (CPG * LL / 2);
    const float4* xp = (const float4*)(x + base);
    const int NV = CPG * LL / 8;   // half-group, in float4
    int tid = threadIdx.x;
    float s1 = 0.f, s2 = 0.f;
    for (int i = tid; i < NV; i += 1024) {
        float4 v = xp[i];
        s1 += v.x + v.y + v.z + v.w;
        s2 += v.x*v.x + v.y*v.y + v.z*v.z + v.w*v.w;
    }
    __shared__ float red[32];
    for (int o = 32; o; o >>= 1) { s1 += __shfl_down(s1, o); s2 += __shfl_down(s2, o); }
    int lane = tid & 63, w = tid >> 6;
    if (!lane) { red[w] = s1; red[16 + w] = s2; }
    __syncthreads();
    if (tid == 0) {
        float a = 0.f, b = 0.f;
        for (int i = 0; i < 16; ++i) { a += red[i]; b += red[16 + i]; }
        stats[gid * 4 + h * 2]     = a;   // raw partial sums
        stats[gid * 4 + h * 2 + 1] = b;
    }
}

// ---------------------------------------------------------------------------
// GroupNorm pass 2 + transpose: x [C,L] fp32 -> Ht [L,C] bf16.
// v15: merges the two gn_stats partials inline; vectorized bf16x8 store.
// ---------------------------------------------------------------------------
__global__ __launch_bounds__(256) void gn_norm_t(const float* __restrict__ x,
    const float* __restrict__ gamma, const float* __restrict__ beta,
    const float* __restrict__ stats, __bf16* __restrict__ Ht) {
    __shared__ float T[64][65];
    int n = blockIdx.z, c0 = blockIdx.y * 64, l0 = blockIdx.x * 64;
    int tid = threadIdx.x;
    int lx = tid & 63, py = tid >> 6;
    const float* xb = x + (size_t)n * CL;
    const float inv_n = 1.f / (float)(CPG * LL);
#pragma unroll
    for (int p = 0; p < 16; ++p) {
        int cl = p * 4 + py;
        int c = c0 + cl;
        int g = c >> 4;
        const float* P = stats + (size_t)(n * GRP + g) * 4;
        float s1 = P[0] + P[2], s2 = P[1] + P[3];
        float mean = s1 * inv_n;
        float var  = s2 * inv_n - mean * mean;
        float rstd = rsqrtf(var + EPSV);
        float sc = gamma[c] * rstd, bi = beta[c] - mean * sc;
        float v = xb[(size_t)c * LL + l0 + lx];
        T[lx][cl] = v * sc + bi;
    }
    __syncthreads();
    __bf16* hb = Ht + (size_t)n * CL;
    const int sub  = tid & 7;    // c-subrange (8 bf16 each)
    const int lrow = tid >> 3;   // 32 rows per pass
#pragma unroll
    for (int p = 0; p < 2; ++p) {
        int ll = p * 32 + lrow;
        bf16x8 v;
#pragma unroll
        for (int s = 0; s < 8; ++s) v[s] = (__bf16)T[ll][sub * 8 + s];
        *(bf16x8*)(hb + (size_t)(l0 + ll) * CCH + c0 + sub * 8) = v;
    }
}

// ---------------------------------------------------------------------------
// bf16 MFMA GEMM body, NT form, swizzled LDS, BK=64 (two 32-k panels).
// EPI: 2 +bias[m]->bf16, 4 +bias[m]+resid->fp32, 5 dual-bias[n] (QK fused)->bf16
// ---------------------------------------------------------------------------
#define BM 128
#define BN 128
#define BK 64

template<int EPI>
__device__ __forceinline__ void gemm_body(
    __bf16* As, __bf16* Bs,
    const __bf16* __restrict__ A, const __bf16* __restrict__ B,
    void* __restrict__ Cv, int M, int N, int K,
    long bsA, long bsB, long bsC, long bsR,
    const float* __restrict__ bias, const float* __restrict__ bias2,
    const float* __restrict__ resid,
    int bx, int by, int bz)
{
    const int tid = threadIdx.x;
    const int l = tid & 63, w = tid >> 6;
    const int wm = w >> 1, wn = w & 1;
    const int m0 = by * BM, n0 = bx * BN;
    A += (long)bz * bsA;
    B += (long)bz * bsB;

    f32x4 acc[4][4];
#pragma unroll
    for (int i = 0; i < 4; ++i)
#pragma unroll
        for (int j = 0; j < 4; ++j) acc[i][j] = f32x4{0.f, 0.f, 0.f, 0.f};

    int jj, cc; swz_src(l, jj, cc);
    const int slot = swz_slot(l & 15, l >> 4);

    const __bf16* Ag = A + (size_t)(m0 + w * 16 + jj) * K + cc * 8;
    const __bf16* Bg = B + (size_t)(n0 + w * 16 + jj) * K + cc * 8;
    char* AsB = (char*)As + w * 1024;
    char* BsB = (char*)Bs + w * 1024;

    for (int k0 = 0; k0 < K; k0 += BK) {
        GLOAD_LDS16(Ag + k0,                      AsB);
        GLOAD_LDS16(Ag + k0 + (size_t)64*K,       AsB + 4096);
        GLOAD_LDS16(Bg + k0,                      BsB);
        GLOAD_LDS16(Bg + k0 + (size_t)64*K,       BsB + 4096);
        GLOAD_LDS16(Ag + k0 + 32,                 AsB + 8192);
        GLOAD_LDS16(Ag + k0 + 32 + (size_t)64*K,  AsB + 8192 + 4096);
        GLOAD_LDS16(Bg + k0 + 32,                 BsB + 8192);
        GLOAD_LDS16(Bg + k0 + 32 + (size_t)64*K,  BsB + 8192 + 4096);
        __syncthreads();
#pragma unroll
        for (int h = 0; h < 2; ++h) {
            bf16x8 ar[4], br[4];
#pragma unroll
            for (int t = 0; t < 4; ++t) {
                ar[t] = *(const bf16x8*)(As + h*4096 + (wm*64 + t*16) * 32 + slot * 8);
                br[t] = *(const bf16x8*)(Bs + h*4096 + (wn*64 + t*16) * 32 + slot * 8);
            }
#pragma unroll
            for (int ti = 0; ti < 4; ++ti)
#pragma unroll
                for (int tj = 0; tj < 4; ++tj)
                    acc[ti][tj] = __builtin_amdgcn_mfma_f32_16x16x32_bf16(
                        ar[ti], br[tj], acc[ti][tj], 0, 0, 0);
        }
        __syncthreads();
    }

    const long cb = (long)bz * bsC;
    // EPI==5: block N-span 128 never straddles the 512 boundary
    const float* bn = (EPI == 5) ? ((n0 < 512) ? bias : (bias2 - 512)) : nullptr;
#pragma unroll
    for (int ti = 0; ti < 4; ++ti) {
#pragma unroll
        for (int r = 0; r < 4; ++r) {
            int m = m0 + wm*64 + ti*16 + (l >> 4)*4 + r;
            float bv = (EPI == 2 || EPI == 4) ? bias[m] : 0.f;
#pragma unroll
            for (int tj = 0; tj < 4; ++tj) {
                int n = n0 + wn*64 + tj*16 + (l & 15);
                float v = acc[ti][tj][r];
                if (EPI == 5) v += bn[n];
                if (EPI == 2 || EPI == 4) v += bv;
                if (EPI == 4) {
                    float rs = resid[(long)bz * bsR + (size_t)m * N + n];
                    ((float*)Cv)[cb + (size_t)m * N + n] = v + rs;
                } else {
                    ((__bf16*)Cv)[cb + (size_t)m * N + n] = (__bf16)v;
                }
            }
        }
    }
}

// ---------------------------------------------------------------------------
// v18: QK-GEMM (1024 work-ids) + V-GEMM (512) in ONE PERSISTENT 768-block
// launch: each block runs TWO adjacent work-ids from its XCD chunk
// sequentially. 768 blocks = 3/CU (all co-resident, LDS 32K x 3 = 96K,
// VGPR-cap 4) -> no straggler wave (v17: 1536 blocks needed 6/CU vs
// residency 4-5 => ~1-block tail). Adjacent ids share the A row-panel (QK)
// -> L2 reuse inside the block. base=(d&7)*192+(d>>3)*2 is even and chunk
// size 192 is even => no block straddles the QK/V boundary at 1024.
// LDS hazard: gemm_body's K-loop ends with __syncthreads; epilogue reads
// only registers -> item 2 staging is safe immediately.
// ---------------------------------------------------------------------------
__global__ __launch_bounds__(256) void gemm_qkv(
    const __bf16* __restrict__ Ht, const __bf16* __restrict__ wqkb,
    __bf16* __restrict__ QKt, const __bf16* __restrict__ wvb,
    __bf16* __restrict__ Vb,
    const float* __restrict__ bq, const float* __restrict__ bk,
    const float* __restrict__ bv)
{
    __shared__ __align__(16) __bf16 As[2 * BM * 32];
    __shared__ __align__(16) __bf16 Bs[2 * BN * 32];
    const int d = blockIdx.x;
    const int base = (d & 7) * 192 + (d >> 3) * 2;   // XCD-chunked, 2 items
#pragma unroll 1
    for (int it = 0; it < 2; ++it) {
        const int wk = base + it;
        if (wk < 1024) {
            // QK: M=L, N=1024, K=512; grid was (8, 32, 4)
            gemm_body<5>(As, Bs, Ht, wqkb, QKt, LL, 1024, CCH,
                         CL, 0, (long)LL * 1024, 0, bq, bk, nullptr,
                         wk & 7, (wk >> 3) & 31, wk >> 8);
        } else {
            // V: M=C, N=L, K=C; grid was (32, 4, 4)
            const int v = wk - 1024;
            gemm_body<2>(As, Bs, wvb, Ht, Vb, CCH, LL, CCH,
                         0, CL, CL, 0, bv, nullptr, nullptr,
                         v & 31, (v >> 5) & 3, v >> 7);
        }
    }
}

// out GEMM (EPI=4), 512 blocks (2/CU, co-resident), XCD-chunked (chunk=64).
__global__ __launch_bounds__(256) void gemm_out(
    const __bf16* __restrict__ wob, const __bf16* __restrict__ Ot,
    float* __restrict__ out, const float* __restrict__ bo,
    const float* __restrict__ xr)
{
    __shared__ __align__(16) __bf16 As[2 * BM * 32];
    __shared__ __align__(16) __bf16 Bs[2 * BN * 32];
    const int d = blockIdx.x;
    const int wk = (d & 7) * 64 + (d >> 3);
    gemm_body<4>(As, Bs, wob, Ot, (void*)out, CCH, LL, CCH,
                 0, CL, CL, CL, bo, nullptr, xr,
                 wk & 31, (wk >> 5) & 3, wk >> 7);
}

// ---------------------------------------------------------------------------
// Flash attention v15 = v7 VERBATIM (empirical best). All 8 perturbations
// regressed (+16..+142us); declared structural floor for this structure.
// ---------------------------------------------------------------------------
#define PSTR 88

__global__ __launch_bounds__(512, 2) void flash_attn(
    const __bf16* __restrict__ QK, const __bf16* __restrict__ Vb,
    __bf16* __restrict__ Ot)
{
    __shared__ __align__(16) __bf16 Ks[16 * 64 * 32];   // [kc:16][j:64][k:32] 64 KB
    __shared__ __align__(16) __bf16 Vs[2 * 512 * 32];   // [jc:2][c:512][j:32] 64 KB
    __shared__ float  Sm[64 * 68];                      // k-half merge, 17 KB
    __shared__ __align__(16) __bf16 Ps[64 * PSTR];      // 11 KB
    __shared__ float Lp[64 * 2];                        // l partials per jh

    const int tid = threadIdx.x;
    const int l = tid & 63, w = tid >> 6;
    const int wi = w & 1, jh = (w >> 1) & 1, kh = w >> 2;
    const int g = l >> 4, c = l & 15;
    // XCD-pair batch pinning (verified r6: FETCH 139->41 MB)
    const int b = (blockIdx.x & 7) >> 1;
    const int qt = ((blockIdx.x >> 3) << 1) | (blockIdx.x & 1);
    const int i0 = qt * 64;
    const size_t bb2 = (size_t)b * LL * QSTR;   // QK batch base
    const size_t bb  = (size_t)b * CL;          // V/O batch base
    const float alpha = 0.044194173824159216f;  // 1/sqrt(512)

    int jj, cc; swz_src(l, jj, cc);
    const int slot = swz_slot(c, g);

    // Q fragments: wave owns rows [i0+wi*32,+32) (2 frags), k-half kh*256
    bf16x8 Qf[2][8];
    {
        const __bf16* Qg = QK + bb2 + (size_t)(i0 + wi*32 + c) * QSTR + kh*256 + g*8;
#pragma unroll
        for (int mi = 0; mi < 2; ++mi)
#pragma unroll
            for (int kc = 0; kc < 8; ++kc)
                Qf[mi][kc] = *(const bf16x8*)(Qg + (size_t)mi*16*QSTR + kc*32);
    }

    f32x4 Oacc[4][4];
#pragma unroll
    for (int mi = 0; mi < 4; ++mi)
#pragma unroll
        for (int ni = 0; ni < 4; ++ni) Oacc[mi][ni] = f32x4{0.f, 0.f, 0.f, 0.f};
    float l_r[4] = {0.f, 0.f, 0.f, 0.f};

    const __bf16* Kb = QK + bb2 + 512;   // K columns of fused buffer
    const __bf16* Vg = Vb + bb;

    // K staging: wave stages kc = {w, w+8}
    auto stageK = [&](int j0) {
#pragma unroll
        for (int q = 0; q < 2; ++q) {
            int kc = q * 8 + w;
#pragma unroll
            for (int p = 0; p < 4; ++p) {
                const __bf16* src = Kb + (size_t)(j0 + p*16 + jj) * QSTR + kc*32 + cc*8;
                GLOAD_LDS16(src, (char*)Ks + kc*4096 + p*1024);
            }
        }
    };
    // V staging: wave stages c-rows [w*64,+64)
    auto stageV = [&](int j0) {
#pragma unroll
        for (int jc = 0; jc < 2; ++jc)
#pragma unroll
            for (int p = 0; p < 4; ++p) {
                const __bf16* src = Vg + (size_t)(w*64 + p*16 + jj) * LL + j0 + jc*32 + cc*8;
                GLOAD_LDS16(src, (char*)Vs + jc*32768 + (w*64 + p*16)*64);
            }
    };

    // export partner frag mi=(1-kh) to Sm (v5 layout; uniform-branch static idx)
    auto expst = [&](const f32x4 (&Sx)[2]) {
        const int er0 = wi*32 + (1 - kh)*16 + g*4;
#pragma unroll
        for (int tj = 0; tj < 2; ++tj)
#pragma unroll
            for (int r = 0; r < 4; ++r)
                Sm[(er0 + r)*68 + (jh*2 + tj)*16 + c] = Sx[tj][r];
    };
    // merge + exp own rows mi=kh
    auto smx = [&](const f32x4 (&Sown)[2]) {
        const int row0 = wi*32 + kh*16 + g*4;
#pragma unroll
        for (int r = 0; r < 4; ++r) {
            float rs = 0.f;
#pragma unroll
            for (int tj = 0; tj < 2; ++tj) {
                float p = __expf((Sown[tj][r] + Sm[(row0 + r)*68 + (jh*2 + tj)*16 + c]) * alpha);
                rs += p;
                Ps[(row0 + r) * PSTR + (jh*2 + tj)*16 + c] = (__bf16)p;
            }
            l_r[r] += rs;
        }
    };

    stageK(0);
    for (int t = 0; t < 64; ++t) {
        __syncthreads();             // B1: K(t) staged; prior PV done
        stageV(t * 64);              // drains at B2

        // S partial: rows [wi*32,+32), cols [jh*32,+32), k-half kh
        f32x4 S[2][2];
#pragma unroll
        for (int mi = 0; mi < 2; ++mi)
#pragma unroll
            for (int tj = 0; tj < 2; ++tj) S[mi][tj] = f32x4{0.f,0.f,0.f,0.f};
        __builtin_amdgcn_s_setprio(1);
#pragma unroll
        for (int kc = 0; kc < 8; ++kc) {
#pragma unroll
            for (int tj = 0; tj < 2; ++tj) {
                bf16x8 kf = *(const bf16x8*)(Ks + (kh*8 + kc)*2048 + (jh*2 + tj)*512 + slot*8);
#pragma unroll
                for (int mi = 0; mi < 2; ++mi)
                    S[mi][tj] = __builtin_amdgcn_mfma_f32_16x16x32_bf16(Qf[mi][kc], kf, S[mi][tj], 0, 0, 0);
            }
        }
        __builtin_amdgcn_s_setprio(0);

        if (kh) expst(S[0]); else expst(S[1]);
        __syncthreads();             // B2: Sm visible; V(t) drained; kf reads done

        if (kh) smx(S[1]); else smx(S[0]);
        __syncthreads();             // B3: Ps visible
        if (t < 63) stageK((t + 1) * 64);   // all waves; drains at next B1 (PV cover)

        // O += P.V^T  (all 64 rows, c-slice [w*64,+64))
        __builtin_amdgcn_s_setprio(1);
#pragma unroll
        for (int jc = 0; jc < 2; ++jc) {
            bf16x8 pa[4];
#pragma unroll
            for (int mi = 0; mi < 4; ++mi)
                pa[mi] = *(const bf16x8*)(Ps + (mi*16 + c) * PSTR + jc*32 + g*8);
#pragma unroll
            for (int ni = 0; ni < 4; ++ni) {
                bf16x8 vf = *(const bf16x8*)(Vs + jc*16384 + (w*64 + ni*16)*32 + slot*8);
#pragma unroll
                for (int mi = 0; mi < 4; ++mi)
                    Oacc[mi][ni] = __builtin_amdgcn_mfma_f32_16x16x32_bf16(pa[mi], vf, Oacc[mi][ni], 0, 0, 0);
            }
        }
        __builtin_amdgcn_s_setprio(0);
    }

    // l: reduce lanes (c) then publish per-(row,jh) partial; combine in epilogue
#pragma unroll
    for (int r = 0; r < 4; ++r) {
        float tot = red_sum16(l_r[r]);
        if (c == 0) Lp[(wi*32 + kh*16 + g*4 + r)*2 + jh] = tot;
    }
    __syncthreads();
#pragma unroll
    for (int mi = 0; mi < 4; ++mi) {
#pragma unroll
        for (int r = 0; r < 4; ++r) {
            int row = mi*16 + g*4 + r;
            float inv = 1.f / (Lp[row*2] + Lp[row*2 + 1]);
#pragma unroll
            for (int ni = 0; ni < 4; ++ni) {
                int col = w*64 + ni*16 + c;
                Ot[bb + (size_t)(i0 + row) * CCH + col] = (__bf16)(Oacc[mi][ni][r] * inv);
            }
        }
    }
}

// ---------------------------------------------------------------------------
extern "C" void kernel_launch(void* const* d_in, const int* in_sizes, int n_in,
                              void* d_out, int out_size, void* d_ws, size_t ws_size,
                              hipStream_t stream) {
    const float* x   = (const float*)d_in[0];
    const float* gnw = (const float*)d_in[1];
    const float* gnb = (const float*)d_in[2];
    const float* wq  = (const float*)d_in[3];
    const float* bq  = (const float*)d_in[4];
    const float* wk  = (const float*)d_in[5];
    const float* bk  = (const float*)d_in[6];
    const float* wv  = (const float*)d_in[7];
    const float* bv  = (const float*)d_in[8];
    const float* wo  = (const float*)d_in[9];
    const float* bo  = (const float*)d_in[10];
    float* out = (float*)d_out;

    // ws (bf16): Ht | QK(2x) | Vb | Ot | Wb(4 weights) | stats  ~= 82 MiB
    __bf16* wsb = (__bf16*)d_ws;
    const size_t NCL = (size_t)NB * CL;
    __bf16* Ht  = wsb;
    __bf16* QKt = Ht + NCL;            // [NB][L][1024]
    __bf16* Vb  = QKt + 2 * NCL;
    __bf16* Ot  = Vb + NCL;
    __bf16* Wb  = Ot + NCL;            // wq|wk|wv|wo bf16, contiguous
    float* stats = (float*)(Wb + (size_t)4 * CCH * CCH);  // [128][4] partials
    __bf16* wqkb = Wb;                             // [1024][512] stacked
    __bf16* wvb  = Wb + (size_t)2 * CCH * CCH;
    __bf16* wob  = Wb + (size_t)3 * CCH * CCH;

    // gn partial-stats (256 blocks) + weight convert (4 blocks), one launch
    gn_stats_w<<<dim3(260), 1024, 0, stream>>>(x, stats, wq, wk, wv, wo, Wb);
    gn_norm_t<<<dim3(LL / 64, CCH / 64, NB), 256, 0, stream>>>(x, gnw, gnb, stats, Ht);

    // fused QK + V GEMMs, persistent 2-items/block, XCD-chunked
    gemm_qkv<<<dim3(768), 256, 0, stream>>>(Ht, wqkb, QKt, wvb, Vb, bq, bk, bv);

    flash_attn<<<dim3(256), 512, 0, stream>>>(QKt, Vb, Ot);

    // out[d][l] = Wo.Ot^T + bo + x  (fp32 out), XCD-chunked mapping
    gemm_out<<<dim3(512), 256, 0, stream>>>(wob, Ot, out, bo, x);
}

// Round 14
// 347.657 us; speedup vs baseline: 1.1084x; 1.1084x over previous
//
#include <hip/hip_runtime.h>
#include <math.h>

#define NB   4
#define CCH  512
#define LL   4096
#define GRP  32
#define CPG  16
#define CL   (CCH*LL)
#define EPSV 1e-5f
#define QSTR 1024   // QK fused row stride

typedef __bf16 bf16x8 __attribute__((ext_vector_type(8)));
typedef __bf16 bf16x4 __attribute__((ext_vector_type(4)));
typedef float  f32x4  __attribute__((ext_vector_type(4)));

#define GLOAD_LDS16(g, l) __builtin_amdgcn_global_load_lds( \
    (const __attribute__((address_space(1))) void*)(g),     \
    (__attribute__((address_space(3))) void*)(l), 16, 0, 0)

// ---------------------------------------------------------------------------
// Corrected XOR-swizzle (verified r6: conflicts 2.5e7 -> 6.3e6).
// ---------------------------------------------------------------------------
__device__ __forceinline__ int swz_slot(int row, int q) {
    return 4 * row + (q ^ ((row >> 1) & 3));
}
__device__ __forceinline__ void swz_src(int l, int& jj, int& cc) {
    jj = l >> 2;
    cc = (l & 3) ^ ((l >> 3) & 3);
}

#define DPPF(x, ctrl) __builtin_bit_cast(float, \
    __builtin_amdgcn_update_dpp(0, __builtin_bit_cast(int, (x)), (ctrl), 0xf, 0xf, false))
__device__ __forceinline__ float red_sum16(float x) {
    x += DPPF(x, 0xB1); x += DPPF(x, 0x4E);
    x += DPPF(x, 0x124); x += DPPF(x, 0x128);
    return x;
}

// ---------------------------------------------------------------------------
// GroupNorm pass 1 (v15): 256 blocks — each handles HALF a (n,g) group so the
// whole 256-CU chip is active. Writes raw partial {s1,s2}; gn_norm_t merges.
// (v18's merge of the weight convert into this launch regressed: 4-block
// straggler tail. Reverted to the standalone tobf16_4.)
// ---------------------------------------------------------------------------
__global__ __launch_bounds__(1024) void gn_stats(const float* __restrict__ x,
                                                 float* __restrict__ stats) {
    int gid = blockIdx.x >> 1, h = blockIdx.x & 1;
    int n = gid >> 5, g = gid & 31;
    size_t base = ((size_t)n * CCH + (size_t)g * CPG) * LL
                + (size_t)h * (CPG * LL / 2);
    const float4* xp = (const float4*)(x + base);
    const int NV = CPG * LL / 8;   // half-group, in float4
    int tid = threadIdx.x;
    float s1 = 0.f, s2 = 0.f;
    for (int i = tid; i < NV; i += 1024) {
        float4 v = xp[i];
        s1 += v.x + v.y + v.z + v.w;
        s2 += v.x*v.x + v.y*v.y + v.z*v.z + v.w*v.w;
    }
    __shared__ float red[32];
    for (int o = 32; o; o >>= 1) { s1 += __shfl_down(s1, o); s2 += __shfl_down(s2, o); }
    int lane = tid & 63, w = tid >> 6;
    if (!lane) { red[w] = s1; red[16 + w] = s2; }
    __syncthreads();
    if (tid == 0) {
        float a = 0.f, b = 0.f;
        for (int i = 0; i < 16; ++i) { a += red[i]; b += red[16 + i]; }
        stats[gid * 4 + h * 2]     = a;   // raw partial sums
        stats[gid * 4 + h * 2 + 1] = b;
    }
}

// ---------------------------------------------------------------------------
// GroupNorm pass 2 + transpose: x [C,L] fp32 -> Ht [L,C] bf16.
// v15: merges the two gn_stats partials inline; vectorized bf16x8 store.
// ---------------------------------------------------------------------------
__global__ __launch_bounds__(256) void gn_norm_t(const float* __restrict__ x,
    const float* __restrict__ gamma, const float* __restrict__ beta,
    const float* __restrict__ stats, __bf16* __restrict__ Ht) {
    __shared__ float T[64][65];
    int n = blockIdx.z, c0 = blockIdx.y * 64, l0 = blockIdx.x * 64;
    int tid = threadIdx.x;
    int lx = tid & 63, py = tid >> 6;
    const float* xb = x + (size_t)n * CL;
    const float inv_n = 1.f / (float)(CPG * LL);
#pragma unroll
    for (int p = 0; p < 16; ++p) {
        int cl = p * 4 + py;
        int c = c0 + cl;
        int g = c >> 4;
        const float* P = stats + (size_t)(n * GRP + g) * 4;
        float s1 = P[0] + P[2], s2 = P[1] + P[3];
        float mean = s1 * inv_n;
        float var  = s2 * inv_n - mean * mean;
        float rstd = rsqrtf(var + EPSV);
        float sc = gamma[c] * rstd, bi = beta[c] - mean * sc;
        float v = xb[(size_t)c * LL + l0 + lx];
        T[lx][cl] = v * sc + bi;
    }
    __syncthreads();
    __bf16* hb = Ht + (size_t)n * CL;
    const int sub  = tid & 7;    // c-subrange (8 bf16 each)
    const int lrow = tid >> 3;   // 32 rows per pass
#pragma unroll
    for (int p = 0; p < 2; ++p) {
        int ll = p * 32 + lrow;
        bf16x8 v;
#pragma unroll
        for (int s = 0; s < 8; ++s) v[s] = (__bf16)T[ll][sub * 8 + s];
        *(bf16x8*)(hb + (size_t)(l0 + ll) * CCH + c0 + sub * 8) = v;
    }
}

// ---------------------------------------------------------------------------
// 4-weight fp32 -> bf16 convert, one launch. grid (256, 4).
// v19: vectorized 8B bf16x4 store (was 4x scalar 2B).
// ---------------------------------------------------------------------------
__global__ __launch_bounds__(256) void tobf16_4(
    const float* __restrict__ s0, const float* __restrict__ s1,
    const float* __restrict__ s2, const float* __restrict__ s3,
    __bf16* __restrict__ dst) {
    const float* sp = (blockIdx.y == 0) ? s0 : (blockIdx.y == 1) ? s1
                    : (blockIdx.y == 2) ? s2 : s3;
    int i = (blockIdx.x * 256 + threadIdx.x) * 4;
    float4 v = *(const float4*)(sp + i);
    bf16x4 o; o[0]=(__bf16)v.x; o[1]=(__bf16)v.y; o[2]=(__bf16)v.z; o[3]=(__bf16)v.w;
    *(bf16x4*)(dst + (size_t)blockIdx.y * CCH * CCH + i) = o;
}

// ---------------------------------------------------------------------------
// bf16 MFMA GEMM body, NT form, swizzled LDS, BK=64 (two 32-k panels).
// EPI: 2 +bias[m]->bf16, 4 +bias[m]+resid->fp32, 5 dual-bias[n] (QK fused)->bf16
// ---------------------------------------------------------------------------
#define BM 128
#define BN 128
#define BK 64

template<int EPI>
__device__ __forceinline__ void gemm_body(
    __bf16* As, __bf16* Bs,
    const __bf16* __restrict__ A, const __bf16* __restrict__ B,
    void* __restrict__ Cv, int M, int N, int K,
    long bsA, long bsB, long bsC, long bsR,
    const float* __restrict__ bias, const float* __restrict__ bias2,
    const float* __restrict__ resid,
    int bx, int by, int bz)
{
    const int tid = threadIdx.x;
    const int l = tid & 63, w = tid >> 6;
    const int wm = w >> 1, wn = w & 1;
    const int m0 = by * BM, n0 = bx * BN;
    A += (long)bz * bsA;
    B += (long)bz * bsB;

    f32x4 acc[4][4];
#pragma unroll
    for (int i = 0; i < 4; ++i)
#pragma unroll
        for (int j = 0; j < 4; ++j) acc[i][j] = f32x4{0.f, 0.f, 0.f, 0.f};

    int jj, cc; swz_src(l, jj, cc);
    const int slot = swz_slot(l & 15, l >> 4);

    const __bf16* Ag = A + (size_t)(m0 + w * 16 + jj) * K + cc * 8;
    const __bf16* Bg = B + (size_t)(n0 + w * 16 + jj) * K + cc * 8;
    char* AsB = (char*)As + w * 1024;
    char* BsB = (char*)Bs + w * 1024;

    for (int k0 = 0; k0 < K; k0 += BK) {
        GLOAD_LDS16(Ag + k0,                      AsB);
        GLOAD_LDS16(Ag + k0 + (size_t)64*K,       AsB + 4096);
        GLOAD_LDS16(Bg + k0,                      BsB);
        GLOAD_LDS16(Bg + k0 + (size_t)64*K,       BsB + 4096);
        GLOAD_LDS16(Ag + k0 + 32,                 AsB + 8192);
        GLOAD_LDS16(Ag + k0 + 32 + (size_t)64*K,  AsB + 8192 + 4096);
        GLOAD_LDS16(Bg + k0 + 32,                 BsB + 8192);
        GLOAD_LDS16(Bg + k0 + 32 + (size_t)64*K,  BsB + 8192 + 4096);
        __syncthreads();
#pragma unroll
        for (int h = 0; h < 2; ++h) {
            bf16x8 ar[4], br[4];
#pragma unroll
            for (int t = 0; t < 4; ++t) {
                ar[t] = *(const bf16x8*)(As + h*4096 + (wm*64 + t*16) * 32 + slot * 8);
                br[t] = *(const bf16x8*)(Bs + h*4096 + (wn*64 + t*16) * 32 + slot * 8);
            }
#pragma unroll
            for (int ti = 0; ti < 4; ++ti)
#pragma unroll
                for (int tj = 0; tj < 4; ++tj)
                    acc[ti][tj] = __builtin_amdgcn_mfma_f32_16x16x32_bf16(
                        ar[ti], br[tj], acc[ti][tj], 0, 0, 0);
        }
        __syncthreads();
    }

    const long cb = (long)bz * bsC;
    // EPI==5: block N-span 128 never straddles the 512 boundary
    const float* bn = (EPI == 5) ? ((n0 < 512) ? bias : (bias2 - 512)) : nullptr;
#pragma unroll
    for (int ti = 0; ti < 4; ++ti) {
#pragma unroll
        for (int r = 0; r < 4; ++r) {
            int m = m0 + wm*64 + ti*16 + (l >> 4)*4 + r;
            float bv = (EPI == 2 || EPI == 4) ? bias[m] : 0.f;
#pragma unroll
            for (int tj = 0; tj < 4; ++tj) {
                int n = n0 + wn*64 + tj*16 + (l & 15);
                float v = acc[ti][tj][r];
                if (EPI == 5) v += bn[n];
                if (EPI == 2 || EPI == 4) v += bv;
                if (EPI == 4) {
                    float rs = resid[(long)bz * bsR + (size_t)m * N + n];
                    ((float*)Cv)[cb + (size_t)m * N + n] = v + rs;
                } else {
                    ((__bf16*)Cv)[cb + (size_t)m * N + n] = (__bf16)v;
                }
            }
        }
    }
}

// ---------------------------------------------------------------------------
// v17 (restored): QK-GEMM (1024 work-ids) + V-GEMM (512) in ONE 1536-block
// launch, one item per block. v18's persistent 2-item variant regressed
// (+30us): serializing items inside a block destroyed the inter-block
// overlap (epilogue of one tile ∥ staging of another) that the scheduler
// provides for free with independent blocks.
// XCD-chunked work mapping (T1, bijective: 1536%8==0): work = (d&7)*192+(d>>3)
// ---------------------------------------------------------------------------
__global__ __launch_bounds__(256) void gemm_qkv(
    const __bf16* __restrict__ Ht, const __bf16* __restrict__ wqkb,
    __bf16* __restrict__ QKt, const __bf16* __restrict__ wvb,
    __bf16* __restrict__ Vb,
    const float* __restrict__ bq, const float* __restrict__ bk,
    const float* __restrict__ bv)
{
    __shared__ __align__(16) __bf16 As[2 * BM * 32];
    __shared__ __align__(16) __bf16 Bs[2 * BN * 32];
    const int d = blockIdx.x;
    const int wk = (d & 7) * 192 + (d >> 3);   // XCD-chunked work id
    if (wk < 1024) {
        // QK: M=L, N=1024, K=512; grid was (8, 32, 4)
        gemm_body<5>(As, Bs, Ht, wqkb, QKt, LL, 1024, CCH,
                     CL, 0, (long)LL * 1024, 0, bq, bk, nullptr,
                     wk & 7, (wk >> 3) & 31, wk >> 8);
    } else {
        // V: M=C, N=L, K=C; grid was (32, 4, 4)
        const int v = wk - 1024;
        gemm_body<2>(As, Bs, wvb, Ht, Vb, CCH, LL, CCH,
                     0, CL, CL, 0, bv, nullptr, nullptr,
                     v & 31, (v >> 5) & 3, v >> 7);
    }
}

// out GEMM (EPI=4), 512 blocks, XCD-chunked mapping (chunk=64).
__global__ __launch_bounds__(256) void gemm_out(
    const __bf16* __restrict__ wob, const __bf16* __restrict__ Ot,
    float* __restrict__ out, const float* __restrict__ bo,
    const float* __restrict__ xr)
{
    __shared__ __align__(16) __bf16 As[2 * BM * 32];
    __shared__ __align__(16) __bf16 Bs[2 * BN * 32];
    const int d = blockIdx.x;
    const int wk = (d & 7) * 64 + (d >> 3);
    gemm_body<4>(As, Bs, wob, Ot, (void*)out, CCH, LL, CCH,
                 0, CL, CL, CL, bo, nullptr, xr,
                 wk & 31, (wk >> 5) & 3, wk >> 7);
}

// ---------------------------------------------------------------------------
// Flash attention v15 = v7 VERBATIM (empirical best). All 8 perturbations
// regressed (+16..+142us); declared structural floor for this structure.
// ---------------------------------------------------------------------------
#define PSTR 88

__global__ __launch_bounds__(512, 2) void flash_attn(
    const __bf16* __restrict__ QK, const __bf16* __restrict__ Vb,
    __bf16* __restrict__ Ot)
{
    __shared__ __align__(16) __bf16 Ks[16 * 64 * 32];   // [kc:16][j:64][k:32] 64 KB
    __shared__ __align__(16) __bf16 Vs[2 * 512 * 32];   // [jc:2][c:512][j:32] 64 KB
    __shared__ float  Sm[64 * 68];                      // k-half merge, 17 KB
    __shared__ __align__(16) __bf16 Ps[64 * PSTR];      // 11 KB
    __shared__ float Lp[64 * 2];                        // l partials per jh

    const int tid = threadIdx.x;
    const int l = tid & 63, w = tid >> 6;
    const int wi = w & 1, jh = (w >> 1) & 1, kh = w >> 2;
    const int g = l >> 4, c = l & 15;
    // XCD-pair batch pinning (verified r6: FETCH 139->41 MB)
    const int b = (blockIdx.x & 7) >> 1;
    const int qt = ((blockIdx.x >> 3) << 1) | (blockIdx.x & 1);
    const int i0 = qt * 64;
    const size_t bb2 = (size_t)b * LL * QSTR;   // QK batch base
    const size_t bb  = (size_t)b * CL;          // V/O batch base
    const float alpha = 0.044194173824159216f;  // 1/sqrt(512)

    int jj, cc; swz_src(l, jj, cc);
    const int slot = swz_slot(c, g);

    // Q fragments: wave owns rows [i0+wi*32,+32) (2 frags), k-half kh*256
    bf16x8 Qf[2][8];
    {
        const __bf16* Qg = QK + bb2 + (size_t)(i0 + wi*32 + c) * QSTR + kh*256 + g*8;
#pragma unroll
        for (int mi = 0; mi < 2; ++mi)
#pragma unroll
            for (int kc = 0; kc < 8; ++kc)
                Qf[mi][kc] = *(const bf16x8*)(Qg + (size_t)mi*16*QSTR + kc*32);
    }

    f32x4 Oacc[4][4];
#pragma unroll
    for (int mi = 0; mi < 4; ++mi)
#pragma unroll
        for (int ni = 0; ni < 4; ++ni) Oacc[mi][ni] = f32x4{0.f, 0.f, 0.f, 0.f};
    float l_r[4] = {0.f, 0.f, 0.f, 0.f};

    const __bf16* Kb = QK + bb2 + 512;   // K columns of fused buffer
    const __bf16* Vg = Vb + bb;

    // K staging: wave stages kc = {w, w+8}
    auto stageK = [&](int j0) {
#pragma unroll
        for (int q = 0; q < 2; ++q) {
            int kc = q * 8 + w;
#pragma unroll
            for (int p = 0; p < 4; ++p) {
                const __bf16* src = Kb + (size_t)(j0 + p*16 + jj) * QSTR + kc*32 + cc*8;
                GLOAD_LDS16(src, (char*)Ks + kc*4096 + p*1024);
            }
        }
    };
    // V staging: wave stages c-rows [w*64,+64)
    auto stageV = [&](int j0) {
#pragma unroll
        for (int jc = 0; jc < 2; ++jc)
#pragma unroll
            for (int p = 0; p < 4; ++p) {
                const __bf16* src = Vg + (size_t)(w*64 + p*16 + jj) * LL + j0 + jc*32 + cc*8;
                GLOAD_LDS16(src, (char*)Vs + jc*32768 + (w*64 + p*16)*64);
            }
    };

    // export partner frag mi=(1-kh) to Sm (v5 layout; uniform-branch static idx)
    auto expst = [&](const f32x4 (&Sx)[2]) {
        const int er0 = wi*32 + (1 - kh)*16 + g*4;
#pragma unroll
        for (int tj = 0; tj < 2; ++tj)
#pragma unroll
            for (int r = 0; r < 4; ++r)
                Sm[(er0 + r)*68 + (jh*2 + tj)*16 + c] = Sx[tj][r];
    };
    // merge + exp own rows mi=kh
    auto smx = [&](const f32x4 (&Sown)[2]) {
        const int row0 = wi*32 + kh*16 + g*4;
#pragma unroll
        for (int r = 0; r < 4; ++r) {
            float rs = 0.f;
#pragma unroll
            for (int tj = 0; tj < 2; ++tj) {
                float p = __expf((Sown[tj][r] + Sm[(row0 + r)*68 + (jh*2 + tj)*16 + c]) * alpha);
                rs += p;
                Ps[(row0 + r) * PSTR + (jh*2 + tj)*16 + c] = (__bf16)p;
            }
            l_r[r] += rs;
        }
    };

    stageK(0);
    for (int t = 0; t < 64; ++t) {
        __syncthreads();             // B1: K(t) staged; prior PV done
        stageV(t * 64);              // drains at B2

        // S partial: rows [wi*32,+32), cols [jh*32,+32), k-half kh
        f32x4 S[2][2];
#pragma unroll
        for (int mi = 0; mi < 2; ++mi)
#pragma unroll
            for (int tj = 0; tj < 2; ++tj) S[mi][tj] = f32x4{0.f,0.f,0.f,0.f};
        __builtin_amdgcn_s_setprio(1);
#pragma unroll
        for (int kc = 0; kc < 8; ++kc) {
#pragma unroll
            for (int tj = 0; tj < 2; ++tj) {
                bf16x8 kf = *(const bf16x8*)(Ks + (kh*8 + kc)*2048 + (jh*2 + tj)*512 + slot*8);
#pragma unroll
                for (int mi = 0; mi < 2; ++mi)
                    S[mi][tj] = __builtin_amdgcn_mfma_f32_16x16x32_bf16(Qf[mi][kc], kf, S[mi][tj], 0, 0, 0);
            }
        }
        __builtin_amdgcn_s_setprio(0);

        if (kh) expst(S[0]); else expst(S[1]);
        __syncthreads();             // B2: Sm visible; V(t) drained; kf reads done

        if (kh) smx(S[1]); else smx(S[0]);
        __syncthreads();             // B3: Ps visible
        if (t < 63) stageK((t + 1) * 64);   // all waves; drains at next B1 (PV cover)

        // O += P.V^T  (all 64 rows, c-slice [w*64,+64))
        __builtin_amdgcn_s_setprio(1);
#pragma unroll
        for (int jc = 0; jc < 2; ++jc) {
            bf16x8 pa[4];
#pragma unroll
            for (int mi = 0; mi < 4; ++mi)
                pa[mi] = *(const bf16x8*)(Ps + (mi*16 + c) * PSTR + jc*32 + g*8);
#pragma unroll
            for (int ni = 0; ni < 4; ++ni) {
                bf16x8 vf = *(const bf16x8*)(Vs + jc*16384 + (w*64 + ni*16)*32 + slot*8);
#pragma unroll
                for (int mi = 0; mi < 4; ++mi)
                    Oacc[mi][ni] = __builtin_amdgcn_mfma_f32_16x16x32_bf16(pa[mi], vf, Oacc[mi][ni], 0, 0, 0);
            }
        }
        __builtin_amdgcn_s_setprio(0);
    }

    // l: reduce lanes (c) then publish per-(row,jh) partial; combine in epilogue
#pragma unroll
    for (int r = 0; r < 4; ++r) {
        float tot = red_sum16(l_r[r]);
        if (c == 0) Lp[(wi*32 + kh*16 + g*4 + r)*2 + jh] = tot;
    }
    __syncthreads();
#pragma unroll
    for (int mi = 0; mi < 4; ++mi) {
#pragma unroll
        for (int r = 0; r < 4; ++r) {
            int row = mi*16 + g*4 + r;
            float inv = 1.f / (Lp[row*2] + Lp[row*2 + 1]);
#pragma unroll
            for (int ni = 0; ni < 4; ++ni) {
                int col = w*64 + ni*16 + c;
                Ot[bb + (size_t)(i0 + row) * CCH + col] = (__bf16)(Oacc[mi][ni][r] * inv);
            }
        }
    }
}

// ---------------------------------------------------------------------------
extern "C" void kernel_launch(void* const* d_in, const int* in_sizes, int n_in,
                              void* d_out, int out_size, void* d_ws, size_t ws_size,
                              hipStream_t stream) {
    const float* x   = (const float*)d_in[0];
    const float* gnw = (const float*)d_in[1];
    const float* gnb = (const float*)d_in[2];
    const float* wq  = (const float*)d_in[3];
    const float* bq  = (const float*)d_in[4];
    const float* wk  = (const float*)d_in[5];
    const float* bk  = (const float*)d_in[6];
    const float* wv  = (const float*)d_in[7];
    const float* bv  = (const float*)d_in[8];
    const float* wo  = (const float*)d_in[9];
    const float* bo  = (const float*)d_in[10];
    float* out = (float*)d_out;

    // ws (bf16): Ht | QK(2x) | Vb | Ot | Wb(4 weights) | stats  ~= 82 MiB
    __bf16* wsb = (__bf16*)d_ws;
    const size_t NCL = (size_t)NB * CL;
    __bf16* Ht  = wsb;
    __bf16* QKt = Ht + NCL;            // [NB][L][1024]
    __bf16* Vb  = QKt + 2 * NCL;
    __bf16* Ot  = Vb + NCL;
    __bf16* Wb  = Ot + NCL;            // wq|wk|wv|wo bf16, contiguous
    float* stats = (float*)(Wb + (size_t)4 * CCH * CCH);  // [128][4] partials
    __bf16* wqkb = Wb;                             // [1024][512] stacked
    __bf16* wvb  = Wb + (size_t)2 * CCH * CCH;
    __bf16* wob  = Wb + (size_t)3 * CCH * CCH;

    tobf16_4<<<dim3(256, 4), 256, 0, stream>>>(wq, wk, wv, wo, Wb);
    gn_stats<<<NB * GRP * 2, 1024, 0, stream>>>(x, stats);
    gn_norm_t<<<dim3(LL / 64, CCH / 64, NB), 256, 0, stream>>>(x, gnw, gnb, stats, Ht);

    // fused QK + V GEMMs (tail-fill), XCD-chunked mapping
    gemm_qkv<<<dim3(1536), 256, 0, stream>>>(Ht, wqkb, QKt, wvb, Vb, bq, bk, bv);

    flash_attn<<<dim3(256), 512, 0, stream>>>(QKt, Vb, Ot);

    // out[d][l] = Wo.Ot^T + bo + x  (fp32 out), XCD-chunked mapping
    gemm_out<<<dim3(512), 256, 0, stream>>>(wob, Ot, out, bo, x);
}

// Round 15
// 346.291 us; speedup vs baseline: 1.1127x; 1.0039x over previous
//
#include <hip/hip_runtime.h>
#include <math.h>

#define NB   4
#define CCH  512
#define LL   4096
#define GRP  32
#define CPG  16
#define CL   (CCH*LL)
#define EPSV 1e-5f
#define QSTR 1024   // QK fused row stride

typedef __bf16 bf16x8 __attribute__((ext_vector_type(8)));
typedef __bf16 bf16x4 __attribute__((ext_vector_type(4)));
typedef float  f32x4  __attribute__((ext_vector_type(4)));

#define GLOAD_LDS16(g, l) __builtin_amdgcn_global_load_lds( \
    (const __attribute__((address_space(1))) void*)(g),     \
    (__attribute__((address_space(3))) void*)(l), 16, 0, 0)

// ---------------------------------------------------------------------------
// Corrected XOR-swizzle (verified r6: conflicts 2.5e7 -> 6.3e6).
// ---------------------------------------------------------------------------
__device__ __forceinline__ int swz_slot(int row, int q) {
    return 4 * row + (q ^ ((row >> 1) & 3));
}
__device__ __forceinline__ void swz_src(int l, int& jj, int& cc) {
    jj = l >> 2;
    cc = (l & 3) ^ ((l >> 3) & 3);
}

#define DPPF(x, ctrl) __builtin_bit_cast(float, \
    __builtin_amdgcn_update_dpp(0, __builtin_bit_cast(int, (x)), (ctrl), 0xf, 0xf, false))
__device__ __forceinline__ float red_sum16(float x) {
    x += DPPF(x, 0xB1); x += DPPF(x, 0x4E);
    x += DPPF(x, 0x124); x += DPPF(x, 0x128);
    return x;
}

// ---------------------------------------------------------------------------
// GroupNorm pass 1 + LOAD-BALANCED weight convert (v20).
// 256 blocks, each: (a) half-(n,g) group raw partial {s1,s2} (v15 scheme);
// (b) converts a 4096-elem slice of the 1M weight elements (16KB read/block,
// perfectly balanced — v18's 4-dedicated-block variant was a straggler).
// Removes the standalone tobf16_4 launch.
// ---------------------------------------------------------------------------
__global__ __launch_bounds__(1024) void gn_stats_w(const float* __restrict__ x,
    float* __restrict__ stats,
    const float* __restrict__ wq, const float* __restrict__ wk,
    const float* __restrict__ wv, const float* __restrict__ wo,
    __bf16* __restrict__ Wb) {
    // (b) weight slice: 64 slices per weight (262144/4096)
    {
        const int slice = blockIdx.x;
        const int wsel = slice >> 6;   // wave-uniform
        const float* sp = (wsel == 0) ? wq : (wsel == 1) ? wk
                        : (wsel == 2) ? wv : wo;
        const int off = (slice & 63) * 4096 + threadIdx.x * 4;
        float4 v = *(const float4*)(sp + off);
        bf16x4 o; o[0]=(__bf16)v.x; o[1]=(__bf16)v.y; o[2]=(__bf16)v.z; o[3]=(__bf16)v.w;
        *(bf16x4*)(Wb + (size_t)wsel * CCH * CCH + off) = o;
    }
    // (a) stats partial
    int gid = blockIdx.x >> 1, h = blockIdx.x & 1;
    int n = gid >> 5, g = gid & 31;
    size_t base = ((size_t)n * CCH + (size_t)g * CPG) * LL
                + (size_t)h * (CPG * LL / 2);
    const float4* xp = (const float4*)(x + base);
    const int NV = CPG * LL / 8;   // half-group, in float4
    int tid = threadIdx.x;
    float s1 = 0.f, s2 = 0.f;
    for (int i = tid; i < NV; i += 1024) {
        float4 v = xp[i];
        s1 += v.x + v.y + v.z + v.w;
        s2 += v.x*v.x + v.y*v.y + v.z*v.z + v.w*v.w;
    }
    __shared__ float red[32];
    for (int o = 32; o; o >>= 1) { s1 += __shfl_down(s1, o); s2 += __shfl_down(s2, o); }
    int lane = tid & 63, w = tid >> 6;
    if (!lane) { red[w] = s1; red[16 + w] = s2; }
    __syncthreads();
    if (tid == 0) {
        float a = 0.f, b = 0.f;
        for (int i = 0; i < 16; ++i) { a += red[i]; b += red[16 + i]; }
        stats[gid * 4 + h * 2]     = a;   // raw partial sums
        stats[gid * 4 + h * 2 + 1] = b;
    }
}

// ---------------------------------------------------------------------------
// GroupNorm pass 2 + transpose: x [C,L] fp32 -> Ht [L,C] bf16.
// v15: merges the two gn_stats partials inline; vectorized bf16x8 store.
// ---------------------------------------------------------------------------
__global__ __launch_bounds__(256) void gn_norm_t(const float* __restrict__ x,
    const float* __restrict__ gamma, const float* __restrict__ beta,
    const float* __restrict__ stats, __bf16* __restrict__ Ht) {
    __shared__ float T[64][65];
    int n = blockIdx.z, c0 = blockIdx.y * 64, l0 = blockIdx.x * 64;
    int tid = threadIdx.x;
    int lx = tid & 63, py = tid >> 6;
    const float* xb = x + (size_t)n * CL;
    const float inv_n = 1.f / (float)(CPG * LL);
#pragma unroll
    for (int p = 0; p < 16; ++p) {
        int cl = p * 4 + py;
        int c = c0 + cl;
        int g = c >> 4;
        const float* P = stats + (size_t)(n * GRP + g) * 4;
        float s1 = P[0] + P[2], s2 = P[1] + P[3];
        float mean = s1 * inv_n;
        float var  = s2 * inv_n - mean * mean;
        float rstd = rsqrtf(var + EPSV);
        float sc = gamma[c] * rstd, bi = beta[c] - mean * sc;
        float v = xb[(size_t)c * LL + l0 + lx];
        T[lx][cl] = v * sc + bi;
    }
    __syncthreads();
    __bf16* hb = Ht + (size_t)n * CL;
    const int sub  = tid & 7;    // c-subrange (8 bf16 each)
    const int lrow = tid >> 3;   // 32 rows per pass
#pragma unroll
    for (int p = 0; p < 2; ++p) {
        int ll = p * 32 + lrow;
        bf16x8 v;
#pragma unroll
        for (int s = 0; s < 8; ++s) v[s] = (__bf16)T[ll][sub * 8 + s];
        *(bf16x8*)(hb + (size_t)(l0 + ll) * CCH + c0 + sub * 8) = v;
    }
}

// ---------------------------------------------------------------------------
// bf16 MFMA GEMM body, NT form, swizzled LDS, BK=64 (two 32-k panels).
// EPI: 2 +bias[m]->bf16, 4 +bias[m]+resid->fp32, 5 dual-bias[n] (QK fused)->bf16
// ---------------------------------------------------------------------------
#define BM 128
#define BN 128
#define BK 64

template<int EPI>
__device__ __forceinline__ void gemm_body(
    __bf16* As, __bf16* Bs,
    const __bf16* __restrict__ A, const __bf16* __restrict__ B,
    void* __restrict__ Cv, int M, int N, int K,
    long bsA, long bsB, long bsC, long bsR,
    const float* __restrict__ bias, const float* __restrict__ bias2,
    const float* __restrict__ resid,
    int bx, int by, int bz)
{
    const int tid = threadIdx.x;
    const int l = tid & 63, w = tid >> 6;
    const int wm = w >> 1, wn = w & 1;
    const int m0 = by * BM, n0 = bx * BN;
    A += (long)bz * bsA;
    B += (long)bz * bsB;

    f32x4 acc[4][4];
#pragma unroll
    for (int i = 0; i < 4; ++i)
#pragma unroll
        for (int j = 0; j < 4; ++j) acc[i][j] = f32x4{0.f, 0.f, 0.f, 0.f};

    int jj, cc; swz_src(l, jj, cc);
    const int slot = swz_slot(l & 15, l >> 4);

    const __bf16* Ag = A + (size_t)(m0 + w * 16 + jj) * K + cc * 8;
    const __bf16* Bg = B + (size_t)(n0 + w * 16 + jj) * K + cc * 8;
    char* AsB = (char*)As + w * 1024;
    char* BsB = (char*)Bs + w * 1024;

    for (int k0 = 0; k0 < K; k0 += BK) {
        GLOAD_LDS16(Ag + k0,                      AsB);
        GLOAD_LDS16(Ag + k0 + (size_t)64*K,       AsB + 4096);
        GLOAD_LDS16(Bg + k0,                      BsB);
        GLOAD_LDS16(Bg + k0 + (size_t)64*K,       BsB + 4096);
        GLOAD_LDS16(Ag + k0 + 32,                 AsB + 8192);
        GLOAD_LDS16(Ag + k0 + 32 + (size_t)64*K,  AsB + 8192 + 4096);
        GLOAD_LDS16(Bg + k0 + 32,                 BsB + 8192);
        GLOAD_LDS16(Bg + k0 + 32 + (size_t)64*K,  BsB + 8192 + 4096);
        __syncthreads();
#pragma unroll
        for (int h = 0; h < 2; ++h) {
            bf16x8 ar[4], br[4];
#pragma unroll
            for (int t = 0; t < 4; ++t) {
                ar[t] = *(const bf16x8*)(As + h*4096 + (wm*64 + t*16) * 32 + slot * 8);
                br[t] = *(const bf16x8*)(Bs + h*4096 + (wn*64 + t*16) * 32 + slot * 8);
            }
#pragma unroll
            for (int ti = 0; ti < 4; ++ti)
#pragma unroll
                for (int tj = 0; tj < 4; ++tj)
                    acc[ti][tj] = __builtin_amdgcn_mfma_f32_16x16x32_bf16(
                        ar[ti], br[tj], acc[ti][tj], 0, 0, 0);
        }
        __syncthreads();
    }

    const long cb = (long)bz * bsC;
    // EPI==5: block N-span 128 never straddles the 512 boundary
    const float* bn = (EPI == 5) ? ((n0 < 512) ? bias : (bias2 - 512)) : nullptr;
#pragma unroll
    for (int ti = 0; ti < 4; ++ti) {
#pragma unroll
        for (int r = 0; r < 4; ++r) {
            int m = m0 + wm*64 + ti*16 + (l >> 4)*4 + r;
            float bv = (EPI == 2 || EPI == 4) ? bias[m] : 0.f;
#pragma unroll
            for (int tj = 0; tj < 4; ++tj) {
                int n = n0 + wn*64 + tj*16 + (l & 15);
                float v = acc[ti][tj][r];
                if (EPI == 5) v += bn[n];
                if (EPI == 2 || EPI == 4) v += bv;
                if (EPI == 4) {
                    float rs = resid[(long)bz * bsR + (size_t)m * N + n];
                    ((float*)Cv)[cb + (size_t)m * N + n] = v + rs;
                } else {
                    ((__bf16*)Cv)[cb + (size_t)m * N + n] = (__bf16)v;
                }
            }
        }
    }
}

// ---------------------------------------------------------------------------
// v17 (kept): QK-GEMM (1024 work-ids) + V-GEMM (512) in ONE 1536-block
// launch, one item per block (v18's 2-item persistent variant regressed).
// XCD-chunked work mapping (T1, bijective: 1536%8==0): work = (d&7)*192+(d>>3)
// ---------------------------------------------------------------------------
__global__ __launch_bounds__(256) void gemm_qkv(
    const __bf16* __restrict__ Ht, const __bf16* __restrict__ wqkb,
    __bf16* __restrict__ QKt, const __bf16* __restrict__ wvb,
    __bf16* __restrict__ Vb,
    const float* __restrict__ bq, const float* __restrict__ bk,
    const float* __restrict__ bv)
{
    __shared__ __align__(16) __bf16 As[2 * BM * 32];
    __shared__ __align__(16) __bf16 Bs[2 * BN * 32];
    const int d = blockIdx.x;
    const int wk = (d & 7) * 192 + (d >> 3);   // XCD-chunked work id
    if (wk < 1024) {
        // QK: M=L, N=1024, K=512; grid was (8, 32, 4)
        gemm_body<5>(As, Bs, Ht, wqkb, QKt, LL, 1024, CCH,
                     CL, 0, (long)LL * 1024, 0, bq, bk, nullptr,
                     wk & 7, (wk >> 3) & 31, wk >> 8);
    } else {
        // V: M=C, N=L, K=C; grid was (32, 4, 4)
        const int v = wk - 1024;
        gemm_body<2>(As, Bs, wvb, Ht, Vb, CCH, LL, CCH,
                     0, CL, CL, 0, bv, nullptr, nullptr,
                     v & 31, (v >> 5) & 3, v >> 7);
    }
}

// out GEMM (EPI=4), 512 blocks, XCD-chunked mapping (chunk=64).
__global__ __launch_bounds__(256) void gemm_out(
    const __bf16* __restrict__ wob, const __bf16* __restrict__ Ot,
    float* __restrict__ out, const float* __restrict__ bo,
    const float* __restrict__ xr)
{
    __shared__ __align__(16) __bf16 As[2 * BM * 32];
    __shared__ __align__(16) __bf16 Bs[2 * BN * 32];
    const int d = blockIdx.x;
    const int wk = (d & 7) * 64 + (d >> 3);
    gemm_body<4>(As, Bs, wob, Ot, (void*)out, CCH, LL, CCH,
                 0, CL, CL, CL, bo, nullptr, xr,
                 wk & 31, (wk >> 5) & 3, wk >> 7);
}

// ---------------------------------------------------------------------------
// Flash attention v15 = v7 VERBATIM (empirical best). All 8 perturbations
// regressed (+16..+142us); declared structural floor for this structure.
// ---------------------------------------------------------------------------
#define PSTR 88

__global__ __launch_bounds__(512, 2) void flash_attn(
    const __bf16* __restrict__ QK, const __bf16* __restrict__ Vb,
    __bf16* __restrict__ Ot)
{
    __shared__ __align__(16) __bf16 Ks[16 * 64 * 32];   // [kc:16][j:64][k:32] 64 KB
    __shared__ __align__(16) __bf16 Vs[2 * 512 * 32];   // [jc:2][c:512][j:32] 64 KB
    __shared__ float  Sm[64 * 68];                      // k-half merge, 17 KB
    __shared__ __align__(16) __bf16 Ps[64 * PSTR];      // 11 KB
    __shared__ float Lp[64 * 2];                        // l partials per jh

    const int tid = threadIdx.x;
    const int l = tid & 63, w = tid >> 6;
    const int wi = w & 1, jh = (w >> 1) & 1, kh = w >> 2;
    const int g = l >> 4, c = l & 15;
    // XCD-pair batch pinning (verified r6: FETCH 139->41 MB)
    const int b = (blockIdx.x & 7) >> 1;
    const int qt = ((blockIdx.x >> 3) << 1) | (blockIdx.x & 1);
    const int i0 = qt * 64;
    const size_t bb2 = (size_t)b * LL * QSTR;   // QK batch base
    const size_t bb  = (size_t)b * CL;          // V/O batch base
    const float alpha = 0.044194173824159216f;  // 1/sqrt(512)

    int jj, cc; swz_src(l, jj, cc);
    const int slot = swz_slot(c, g);

    // Q fragments: wave owns rows [i0+wi*32,+32) (2 frags), k-half kh*256
    bf16x8 Qf[2][8];
    {
        const __bf16* Qg = QK + bb2 + (size_t)(i0 + wi*32 + c) * QSTR + kh*256 + g*8;
#pragma unroll
        for (int mi = 0; mi < 2; ++mi)
#pragma unroll
            for (int kc = 0; kc < 8; ++kc)
                Qf[mi][kc] = *(const bf16x8*)(Qg + (size_t)mi*16*QSTR + kc*32);
    }

    f32x4 Oacc[4][4];
#pragma unroll
    for (int mi = 0; mi < 4; ++mi)
#pragma unroll
        for (int ni = 0; ni < 4; ++ni) Oacc[mi][ni] = f32x4{0.f, 0.f, 0.f, 0.f};
    float l_r[4] = {0.f, 0.f, 0.f, 0.f};

    const __bf16* Kb = QK + bb2 + 512;   // K columns of fused buffer
    const __bf16* Vg = Vb + bb;

    // K staging: wave stages kc = {w, w+8}
    auto stageK = [&](int j0) {
#pragma unroll
        for (int q = 0; q < 2; ++q) {
            int kc = q * 8 + w;
#pragma unroll
            for (int p = 0; p < 4; ++p) {
                const __bf16* src = Kb + (size_t)(j0 + p*16 + jj) * QSTR + kc*32 + cc*8;
                GLOAD_LDS16(src, (char*)Ks + kc*4096 + p*1024);
            }
        }
    };
    // V staging: wave stages c-rows [w*64,+64)
    auto stageV = [&](int j0) {
#pragma unroll
        for (int jc = 0; jc < 2; ++jc)
#pragma unroll
            for (int p = 0; p < 4; ++p) {
                const __bf16* src = Vg + (size_t)(w*64 + p*16 + jj) * LL + j0 + jc*32 + cc*8;
                GLOAD_LDS16(src, (char*)Vs + jc*32768 + (w*64 + p*16)*64);
            }
    };

    // export partner frag mi=(1-kh) to Sm (v5 layout; uniform-branch static idx)
    auto expst = [&](const f32x4 (&Sx)[2]) {
        const int er0 = wi*32 + (1 - kh)*16 + g*4;
#pragma unroll
        for (int tj = 0; tj < 2; ++tj)
#pragma unroll
            for (int r = 0; r < 4; ++r)
                Sm[(er0 + r)*68 + (jh*2 + tj)*16 + c] = Sx[tj][r];
    };
    // merge + exp own rows mi=kh
    auto smx = [&](const f32x4 (&Sown)[2]) {
        const int row0 = wi*32 + kh*16 + g*4;
#pragma unroll
        for (int r = 0; r < 4; ++r) {
            float rs = 0.f;
#pragma unroll
            for (int tj = 0; tj < 2; ++tj) {
                float p = __expf((Sown[tj][r] + Sm[(row0 + r)*68 + (jh*2 + tj)*16 + c]) * alpha);
                rs += p;
                Ps[(row0 + r) * PSTR + (jh*2 + tj)*16 + c] = (__bf16)p;
            }
            l_r[r] += rs;
        }
    };

    stageK(0);
    for (int t = 0; t < 64; ++t) {
        __syncthreads();             // B1: K(t) staged; prior PV done
        stageV(t * 64);              // drains at B2

        // S partial: rows [wi*32,+32), cols [jh*32,+32), k-half kh
        f32x4 S[2][2];
#pragma unroll
        for (int mi = 0; mi < 2; ++mi)
#pragma unroll
            for (int tj = 0; tj < 2; ++tj) S[mi][tj] = f32x4{0.f,0.f,0.f,0.f};
        __builtin_amdgcn_s_setprio(1);
#pragma unroll
        for (int kc = 0; kc < 8; ++kc) {
#pragma unroll
            for (int tj = 0; tj < 2; ++tj) {
                bf16x8 kf = *(const bf16x8*)(Ks + (kh*8 + kc)*2048 + (jh*2 + tj)*512 + slot*8);
#pragma unroll
                for (int mi = 0; mi < 2; ++mi)
                    S[mi][tj] = __builtin_amdgcn_mfma_f32_16x16x32_bf16(Qf[mi][kc], kf, S[mi][tj], 0, 0, 0);
            }
        }
        __builtin_amdgcn_s_setprio(0);

        if (kh) expst(S[0]); else expst(S[1]);
        __syncthreads();             // B2: Sm visible; V(t) drained; kf reads done

        if (kh) smx(S[1]); else smx(S[0]);
        __syncthreads();             // B3: Ps visible
        if (t < 63) stageK((t + 1) * 64);   // all waves; drains at next B1 (PV cover)

        // O += P.V^T  (all 64 rows, c-slice [w*64,+64))
        __builtin_amdgcn_s_setprio(1);
#pragma unroll
        for (int jc = 0; jc < 2; ++jc) {
            bf16x8 pa[4];
#pragma unroll
            for (int mi = 0; mi < 4; ++mi)
                pa[mi] = *(const bf16x8*)(Ps + (mi*16 + c) * PSTR + jc*32 + g*8);
#pragma unroll
            for (int ni = 0; ni < 4; ++ni) {
                bf16x8 vf = *(const bf16x8*)(Vs + jc*16384 + (w*64 + ni*16)*32 + slot*8);
#pragma unroll
                for (int mi = 0; mi < 4; ++mi)
                    Oacc[mi][ni] = __builtin_amdgcn_mfma_f32_16x16x32_bf16(pa[mi], vf, Oacc[mi][ni], 0, 0, 0);
            }
        }
        __builtin_amdgcn_s_setprio(0);
    }

    // l: reduce lanes (c) then publish per-(row,jh) partial; combine in epilogue
#pragma unroll
    for (int r = 0; r < 4; ++r) {
        float tot = red_sum16(l_r[r]);
        if (c == 0) Lp[(wi*32 + kh*16 + g*4 + r)*2 + jh] = tot;
    }
    __syncthreads();
#pragma unroll
    for (int mi = 0; mi < 4; ++mi) {
#pragma unroll
        for (int r = 0; r < 4; ++r) {
            int row = mi*16 + g*4 + r;
            float inv = 1.f / (Lp[row*2] + Lp[row*2 + 1]);
#pragma unroll
            for (int ni = 0; ni < 4; ++ni) {
                int col = w*64 + ni*16 + c;
                Ot[bb + (size_t)(i0 + row) * CCH + col] = (__bf16)(Oacc[mi][ni][r] * inv);
            }
        }
    }
}

// ---------------------------------------------------------------------------
extern "C" void kernel_launch(void* const* d_in, const int* in_sizes, int n_in,
                              void* d_out, int out_size, void* d_ws, size_t ws_size,
                              hipStream_t stream) {
    const float* x   = (const float*)d_in[0];
    const float* gnw = (const float*)d_in[1];
    const float* gnb = (const float*)d_in[2];
    const float* wq  = (const float*)d_in[3];
    const float* bq  = (const float*)d_in[4];
    const float* wk  = (const float*)d_in[5];
    const float* bk  = (const float*)d_in[6];
    const float* wv  = (const float*)d_in[7];
    const float* bv  = (const float*)d_in[8];
    const float* wo  = (const float*)d_in[9];
    const float* bo  = (const float*)d_in[10];
    float* out = (float*)d_out;

    // ws (bf16): Ht | QK(2x) | Vb | Ot | Wb(4 weights) | stats  ~= 82 MiB
    __bf16* wsb = (__bf16*)d_ws;
    const size_t NCL = (size_t)NB * CL;
    __bf16* Ht  = wsb;
    __bf16* QKt = Ht + NCL;            // [NB][L][1024]
    __bf16* Vb  = QKt + 2 * NCL;
    __bf16* Ot  = Vb + NCL;
    __bf16* Wb  = Ot + NCL;            // wq|wk|wv|wo bf16, contiguous
    float* stats = (float*)(Wb + (size_t)4 * CCH * CCH);  // [128][4] partials
    __bf16* wqkb = Wb;                             // [1024][512] stacked
    __bf16* wvb  = Wb + (size_t)2 * CCH * CCH;
    __bf16* wob  = Wb + (size_t)3 * CCH * CCH;

    // gn partial-stats + load-balanced weight convert, one 256-block launch
    gn_stats_w<<<dim3(NB * GRP * 2), 1024, 0, stream>>>(x, stats, wq, wk, wv, wo, Wb);
    gn_norm_t<<<dim3(LL / 64, CCH / 64, NB), 256, 0, stream>>>(x, gnw, gnb, stats, Ht);

    // fused QK + V GEMMs (tail-fill), XCD-chunked mapping
    gemm_qkv<<<dim3(1536), 256, 0, stream>>>(Ht, wqkb, QKt, wvb, Vb, bq, bk, bv);

    flash_attn<<<dim3(256), 512, 0, stream>>>(QKt, Vb, Ot);

    // out[d][l] = Wo.Ot^T + bo + x  (fp32 out), XCD-chunked mapping
    gemm_out<<<dim3(512), 256, 0, stream>>>(wob, Ot, out, bo, x);
}